// Round 17
// baseline (114.027 us; speedup 1.0000x reference)
//
#include <hip/hip_runtime.h>
#include <hip/hip_bf16.h>
#include <stdint.h>

typedef __attribute__((ext_vector_type(4))) float f32x4;
typedef __attribute__((ext_vector_type(8))) __bf16 bf16x8;
typedef __attribute__((ext_vector_type(4))) __bf16 bf16x4;

#define DEVI __device__ __forceinline__

static constexpr int S_  = 2048;
static constexpr int D_  = 1024;
static constexpr int H_  = 16;
static constexpr int HD_ = 64;
static constexpr int M_  = 2 * S_;   // B*S = 4096 token rows
static constexpr float SCL2 = 0.18033688f;  // 0.125 * log2(e)

DEVI void gload_lds16(const void* gsrc, void* ldst) {
  __builtin_amdgcn_global_load_lds(
      (__attribute__((address_space(1))) void*)(void*)gsrc,
      (__attribute__((address_space(3))) void*)ldst, 16, 0, 0);
}

DEVI float fexp2(float x) {
  float r;
  asm("v_exp_f32 %0, %1" : "=v"(r) : "v"(x));
  return r;
}

// Fused conversion kernel: x + 4 weights fp32->bf16 (32B-read/16B-write per
// thread), plus RoPE table. Round-16 version, unchanged.
__global__ __launch_bounds__(256) void cvt_all_kernel(
    const float* __restrict__ x, const float* __restrict__ wq,
    const float* __restrict__ wk, const float* __restrict__ wv,
    const float* __restrict__ wo,
    __bf16* __restrict__ xb, __bf16* __restrict__ wqb,
    __bf16* __restrict__ wkb, __bf16* __restrict__ wvb,
    __bf16* __restrict__ wob, float* __restrict__ tab) {
  int blk = blockIdx.x;
  if (blk < 4096) {
    int i = blk * 256 + threadIdx.x;     // float8 index (1M total)
    const float* src; __bf16* dst; int off;
    if (i < (1 << 19))                      { src = x;  dst = xb;  off = 0; }
    else if (i < (1 << 19) + (1 << 17))     { src = wq; dst = wqb; off = (1 << 19); }
    else if (i < (1 << 19) + 2 * (1 << 17)) { src = wk; dst = wkb; off = (1 << 19) + (1 << 17); }
    else if (i < (1 << 19) + 3 * (1 << 17)) { src = wv; dst = wvb; off = (1 << 19) + 2 * (1 << 17); }
    else                                    { src = wo; dst = wob; off = (1 << 19) + 3 * (1 << 17); }
    int j = i - off;
    float4 v0 = reinterpret_cast<const float4*>(src)[2 * j];
    float4 v1 = reinterpret_cast<const float4*>(src)[2 * j + 1];
    bf16x8 o;
    o[0] = (__bf16)v0.x; o[1] = (__bf16)v0.y; o[2] = (__bf16)v0.z; o[3] = (__bf16)v0.w;
    o[4] = (__bf16)v1.x; o[5] = (__bf16)v1.y; o[6] = (__bf16)v1.z; o[7] = (__bf16)v1.w;
    reinterpret_cast<bf16x8*>(dst)[j] = o;
  } else {
    int i = (blk - 4096) * 256 + threadIdx.x;   // 0..65535 = S*32
    int s = i >> 5, f = i & 31;
    float freq = powf(10000.0f, -(float)(2 * f) / (float)HD_);
    float ang = (float)s * freq;
    tab[2 * i]     = cosf(ang);
    tab[2 * i + 1] = sinf(ang);
  }
}

// ---------------------------------------------------------------------------
// QKV GEMM: bt0-clone structure -- tile 128x64, BK=32, 512-thread / 8-wave
// blocks (wave grid 4M x 2N, 32x32 per wave). Grid (32,16,3) = 1536 blocks
// = 6/CU -> 4 resident = 32 waves/CU (full cap; the 128x128 version was
// grid-limited to 24). A staged by all 8 waves, B by waves 0..3.
// z=0/1 -> RoPE + head-split (Q pre-scaled by SCL2);
// z=2 -> V written DIRECTLY TRANSPOSED as Vt[bh][d][s].
// ---------------------------------------------------------------------------
__global__ __launch_bounds__(512, 8) void gemm_qkv(
    const __bf16* __restrict__ A, const __bf16* __restrict__ W0,
    const __bf16* __restrict__ W1, const __bf16* __restrict__ W2,
    __bf16* __restrict__ Cq, __bf16* __restrict__ Ck, __bf16* __restrict__ Cvt,
    const float* __restrict__ tab) {
  __shared__ __attribute__((aligned(16))) __bf16 As[128 * 32];
  __shared__ __attribute__((aligned(16))) __bf16 Bs[64 * 32];
  const int tid  = threadIdx.x;
  const int lane = tid & 63;
  const int wv   = tid >> 6;
  const int wr   = wv >> 1;            // 0..3 (M strip of 32)
  const int wc   = wv & 1;             // 0..1 (N strip of 32)
  const int m0 = blockIdx.x * 128;
  const int n0 = blockIdx.y * 64;
  const int z  = blockIdx.z;
  const __bf16* W = (z == 0) ? W0 : (z == 1 ? W1 : W2);
  const int arow = lane & 15;
  const int kgrp = (lane >> 4) * 8;

  f32x4 acc[2][2];
#pragma unroll
  for (int i = 0; i < 2; i++)
#pragma unroll
    for (int j = 0; j < 2; j++) acc[i][j] = f32x4{0.f, 0.f, 0.f, 0.f};

  for (int k0 = 0; k0 < 1024; k0 += 32) {
    __syncthreads();
    {
      int c   = wv * 64 + lane;        // 0..511 -> A rows 0..127
      int row = c >> 2;
      int kc  = (c & 3) * 8;
      gload_lds16(A + (size_t)(m0 + row) * 1024 + k0 + kc, As + wv * 512);
      if (wv < 4)                      // 0..255 -> B rows 0..63
        gload_lds16(W + (size_t)(n0 + row) * 1024 + k0 + kc, Bs + wv * 512);
    }
    asm volatile("s_waitcnt vmcnt(0)" ::: "memory");
    __syncthreads();
    bf16x8 af[2], bw[2];
#pragma unroll
    for (int i = 0; i < 2; i++)
      af[i] = *reinterpret_cast<const bf16x8*>(As + (wr * 32 + i * 16 + arow) * 32 + kgrp);
#pragma unroll
    for (int j = 0; j < 2; j++)
      bw[j] = *reinterpret_cast<const bf16x8*>(Bs + (wc * 32 + j * 16 + arow) * 32 + kgrp);
#pragma unroll
    for (int i = 0; i < 2; i++)
#pragma unroll
      for (int j = 0; j < 2; j++)
        acc[i][j] = __builtin_amdgcn_mfma_f32_16x16x32_bf16(af[i], bw[j], acc[i][j], 0, 0, 0);
  }

  // epilogue. C/D layout: col = lane&15 (n), row = (lane>>4)*4 + r (m)
  if (z == 2) {
#pragma unroll
    for (int i = 0; i < 2; i++) {
      int m = m0 + wr * 32 + i * 16 + (lane >> 4) * 4;
      int bb = m >> 11, srow = m & (S_ - 1);
#pragma unroll
      for (int j = 0; j < 2; j++) {
        int n = n0 + wc * 32 + j * 16 + arow;
        int h = n >> 6, d = n & 63;
        bf16x4 o4;
#pragma unroll
        for (int r = 0; r < 4; r++) o4[r] = (__bf16)acc[i][j][r];
        *reinterpret_cast<bf16x4*>(
            Cvt + ((size_t)(bb * H_ + h) * HD_ + d) * S_ + srow) = o4;
      }
    }
  } else {
#pragma unroll
    for (int i = 0; i < 2; i++) {
#pragma unroll
      for (int j = 0; j < 2; j++) {
#pragma unroll
        for (int r = 0; r < 4; r++) {
          int m = m0 + wr * 32 + i * 16 + (lane >> 4) * 4 + r;
          int n = n0 + wc * 32 + j * 16 + arow;
          float v = acc[i][j][r];
          int bb = m >> 11, srow = m & (S_ - 1);
          int h = n >> 6, d = n & 63;
          size_t oidx = ((size_t)(bb * H_ + h) * S_ + srow) * HD_ + d;
          float other = __shfl_xor(v, 1, 64);   // n bit0 == lane bit0
          int fq = d >> 1;
          float2 cssn = *reinterpret_cast<const float2*>(tab + (srow * 32 + fq) * 2);
          float rv = (d & 1) ? (other * cssn.y + v * cssn.x)
                             : (v * cssn.x - other * cssn.y);
          if (z == 0) rv *= SCL2;   // pre-scale Q: logits in exp2 domain
          ((z == 0) ? Cq : Ck)[oidx] = (__bf16)rv;
        }
      }
    }
  }
}

// ---------------------------------------------------------------------------
// O-projection: tile 128x64, 512-thread / 8-wave blocks. Proven round-11
// kernel, unchanged.
// ---------------------------------------------------------------------------
__global__ __launch_bounds__(512, 4) void gemm_bt0(
    const __bf16* __restrict__ A, const __bf16* __restrict__ W0,
    float* __restrict__ Cf) {
  __shared__ __attribute__((aligned(16))) __bf16 As[128 * 32];
  __shared__ __attribute__((aligned(16))) __bf16 Bs[64 * 32];
  const int tid  = threadIdx.x;
  const int lane = tid & 63;
  const int wv   = tid >> 6;
  const int wr   = wv >> 1;            // 0..3 (M strip of 32)
  const int wc   = wv & 1;             // 0..1 (N strip of 32)
  const int m0 = blockIdx.x * 128;
  const int n0 = blockIdx.y * 64;
  const int arow = lane & 15;
  const int kgrp = (lane >> 4) * 8;

  f32x4 acc[2][2];
#pragma unroll
  for (int i = 0; i < 2; i++)
#pragma unroll
    for (int j = 0; j < 2; j++) acc[i][j] = f32x4{0.f, 0.f, 0.f, 0.f};

  for (int k0 = 0; k0 < 1024; k0 += 32) {
    __syncthreads();
    {
      int c   = wv * 64 + lane;        // 0..511 -> A rows 0..127
      int row = c >> 2;
      int kc  = (c & 3) * 8;
      gload_lds16(A + (size_t)(m0 + row) * 1024 + k0 + kc, As + wv * 512);
      if (wv < 4)                      // 0..255 -> B rows 0..63
        gload_lds16(W0 + (size_t)(n0 + row) * 1024 + k0 + kc, Bs + wv * 512);
    }
    asm volatile("s_waitcnt vmcnt(0)" ::: "memory");
    __syncthreads();
    bf16x8 af[2], bw[2];
#pragma unroll
    for (int i = 0; i < 2; i++)
      af[i] = *reinterpret_cast<const bf16x8*>(As + (wr * 32 + i * 16 + arow) * 32 + kgrp);
#pragma unroll
    for (int j = 0; j < 2; j++)
      bw[j] = *reinterpret_cast<const bf16x8*>(Bs + (wc * 32 + j * 16 + arow) * 32 + kgrp);
#pragma unroll
    for (int i = 0; i < 2; i++)
#pragma unroll
      for (int j = 0; j < 2; j++)
        acc[i][j] = __builtin_amdgcn_mfma_f32_16x16x32_bf16(af[i], bw[j], acc[i][j], 0, 0, 0);
  }

#pragma unroll
  for (int i = 0; i < 2; i++)
#pragma unroll
    for (int j = 0; j < 2; j++)
#pragma unroll
      for (int r = 0; r < 4; r++) {
        int m = m0 + wr * 32 + i * 16 + (lane >> 4) * 4 + r;
        int n = n0 + wc * 32 + j * 16 + arow;
        Cf[(size_t)m * D_ + n] = acc[i][j][r];
      }
}

// ---------------------------------------------------------------------------
// Flash attention, causal. Round-14 version (best measured): 512 linear
// blocks, 8 waves each, one 128-row Q-tile per block; heavy/light halves
// for LPT-style balance; tree softmax; KVBLK=128; counted vmcnt(4) dbuf.
// ---------------------------------------------------------------------------
__global__ __launch_bounds__(512, 4) void attn_kernel(
    const __bf16* __restrict__ Q, const __bf16* __restrict__ K,
    const __bf16* __restrict__ Vt, __bf16* __restrict__ O) {
  __shared__ __attribute__((aligned(16))) __bf16 Ks[2][128 * 64];
  __shared__ __attribute__((aligned(16))) __bf16 Vs[2][64 * 128];
  const int tid = threadIdx.x, lane = tid & 63, wv = tid >> 6;  // wv 0..7
  const int id   = blockIdx.x;        // 0..511
  const int half = id >> 8;           // 0 = heavy tiles, 1 = light tiles
  const int sub  = id & 255;
  const int bh   = sub & 31;
  const int pr   = sub >> 5;          // 0..7
  const int qt   = half ? pr : 15 - pr;   // heavy half dispatched first
  const int b = bh >> 4, h = bh & 15;
  const __bf16* Qb  = Q  + (size_t)bh * S_ * HD_;
  const __bf16* Kb  = K  + (size_t)bh * S_ * HD_;
  const __bf16* Vtb = Vt + (size_t)bh * HD_ * S_;
  const int arow = lane & 15, g = lane >> 4;

  // 4 gload_lds16 per thread per 128-key tile (2 K-chunks + 2 V-chunks)
#define STAGE(K0, BK_, BV_)                                                   \
  do {                                                                        \
    _Pragma("unroll") for (int j = 0; j < 2; ++j) {                           \
      int c = (wv * 2 + j) * 64 + lane;          /* chunk 0..1023 */          \
      int rowk = c >> 3, qqk = c & 7;                                         \
      int qsk = qqk ^ (rowk & 7);                                             \
      int ctp = rowk >> 4, rw = rowk & 15;                                    \
      int kph = ((ctp & 4) << 4) + ((ctp & 2) << 4) + ((ctp & 1) << 2)        \
                + ((rw >> 2) << 3) + (rw & 3);                                \
      gload_lds16(Kb + (size_t)((K0) + kph) * HD_ + qsk * 8,                  \
                  (BK_) + (size_t)(wv * 2 + j) * 512);                        \
      int rowv = c >> 4, qqv = c & 15;                                        \
      int qsv = qqv ^ (rowv & 7);                                             \
      gload_lds16(Vtb + (size_t)rowv * S_ + (K0) + qsv * 8,                   \
                  (BV_) + (size_t)(wv * 2 + j) * 512);                        \
    }                                                                         \
  } while (0)

  const int q0 = qt * 128;
  const int nkv = qt + 1;                     // 128-key tiles
  const int qw = q0 + wv * 16;
  const int qg = qw + arow;                   // this thread's q-row

  bf16x8 aq[2];
#pragma unroll
  for (int j = 0; j < 2; j++)
    aq[j] = *reinterpret_cast<const bf16x8*>(
        Qb + (size_t)(qw + arow) * HD_ + j * 32 + g * 8);

  f32x4 po[4];
#pragma unroll
  for (int dt = 0; dt < 4; dt++) po[dt] = f32x4{0.f, 0.f, 0.f, 0.f};
  float mrow = -1e30f, lrow = 0.f;

  // prologue: stage tiles 0 and 1 (clamped); vmcnt(4) -> tile 0 landed
  STAGE(0, Ks[0], Vs[0]);
  {
    int t1 = (nkv > 1) ? 128 : 0;
    STAGE(t1, Ks[1], Vs[1]);
  }
  asm volatile("s_waitcnt vmcnt(4)" ::: "memory");
  __builtin_amdgcn_s_barrier();

  for (int kt = 0; kt < nkv; ++kt) {
    const int k0 = kt * 128;
    const int cur = kt & 1;
    const __bf16* Kc = Ks[cur];
    const __bf16* Vc = Vs[cur];

    // S^T = K Q^T : D[key][q], 16 MFMA over 128 keys
    f32x4 sc4[8];
    __builtin_amdgcn_s_setprio(1);
#pragma unroll
    for (int ct = 0; ct < 8; ct++) {
      sc4[ct] = f32x4{0.f, 0.f, 0.f, 0.f};
      int L = ct * 16 + arow;
#pragma unroll
      for (int j2 = 0; j2 < 2; j2++) {
        int byt = (L * 128 + j2 * 64 + g * 16) ^ ((L & 7) << 4);
        bf16x8 kb = *reinterpret_cast<const bf16x8*>((const char*)Kc + byt);
        sc4[ct] = __builtin_amdgcn_mfma_f32_16x16x32_bf16(kb, aq[j2], sc4[ct], 0, 0, 0);
      }
    }
    __builtin_amdgcn_s_setprio(0);

    // causal mask (last tile only). physical key of sc4[ct][r]:
    // k0 + (ct&4)*16 + (ct&2)*16 + (ct&1)*4 + g*8 + r
    if (kt == nkv - 1) {
#pragma unroll
      for (int ct = 0; ct < 8; ct++) {
        int kb0 = k0 + ((ct & 4) << 4) + ((ct & 2) << 4) + ((ct & 1) << 2) + g * 8;
#pragma unroll
        for (int r = 0; r < 4; r++)
          if (kb0 + r > qg) sc4[ct][r] = -1e30f;
      }
    }

    // in-register online softmax (one q-row per lane, 32 values), tree max
    float mc[8];
#pragma unroll
    for (int ct = 0; ct < 8; ct++)
      mc[ct] = fmaxf(fmaxf(sc4[ct][0], sc4[ct][1]),
                     fmaxf(sc4[ct][2], sc4[ct][3]));
#pragma unroll
    for (int sstep = 4; sstep > 0; sstep >>= 1)
#pragma unroll
      for (int ct = 0; ct < sstep; ct++) mc[ct] = fmaxf(mc[ct], mc[ct + sstep]);
    float mx = mc[0];
    mx = fmaxf(mx, __shfl_xor(mx, 16, 64));
    mx = fmaxf(mx, __shfl_xor(mx, 32, 64));

    bool noskip = !__all(mx <= mrow + 11.0f);
    if (noskip) {
      float mnew = fmaxf(mrow, mx);
      float corr = fexp2(mrow - mnew);
      mrow = mnew;
      lrow *= corr;
#pragma unroll
      for (int dt = 0; dt < 4; dt++)
#pragma unroll
        for (int r = 0; r < 4; r++) po[dt][r] *= corr;
    }

    // exp + tree sum
    float rc[8];
#pragma unroll
    for (int ct = 0; ct < 8; ct++) {
      float e0 = fexp2(sc4[ct][0] - mrow);
      float e1 = fexp2(sc4[ct][1] - mrow);
      float e2 = fexp2(sc4[ct][2] - mrow);
      float e3 = fexp2(sc4[ct][3] - mrow);
      sc4[ct][0] = e0; sc4[ct][1] = e1; sc4[ct][2] = e2; sc4[ct][3] = e3;
      rc[ct] = (e0 + e1) + (e2 + e3);
    }
#pragma unroll
    for (int sstep = 4; sstep > 0; sstep >>= 1)
#pragma unroll
      for (int ct = 0; ct < sstep; ct++) rc[ct] += rc[ct + sstep];
    float rs = rc[0];
    rs += __shfl_xor(rs, 16, 64);
    rs += __shfl_xor(rs, 32, 64);
    lrow += rs;

    // pack P: pb[jj] holds physical keys jj*32 + g*8 .. +7 (lane-local)
    bf16x8 pb[4];
#pragma unroll
    for (int h2 = 0; h2 < 2; h2++)
#pragma unroll
      for (int j2 = 0; j2 < 2; j2++) {
#pragma unroll
        for (int r = 0; r < 4; r++) {
          pb[h2 * 2 + j2][r]     = (__bf16)sc4[h2 * 4 + 2 * j2][r];
          pb[h2 * 2 + j2][4 + r] = (__bf16)sc4[h2 * 4 + 2 * j2 + 1][r];
        }
      }

    // O^T += V^T P^T : po[dt] = D[d][q], d = dt*16 + g*4 + r, q = arow
    __builtin_amdgcn_s_setprio(1);
#pragma unroll
    for (int dt = 0; dt < 4; dt++) {
      int d = dt * 16 + arow;
#pragma unroll
      for (int jj = 0; jj < 4; jj++) {
        int byv = (d * 256 + jj * 64 + g * 16) ^ ((d & 7) << 4);
        bf16x8 vb = *reinterpret_cast<const bf16x8*>((const char*)Vc + byv);
        po[dt] = __builtin_amdgcn_mfma_f32_16x16x32_bf16(vb, pb[jj], po[dt], 0, 0, 0);
      }
    }
    __builtin_amdgcn_s_setprio(0);

    // pipeline tail: all waves done reading buf[cur], then stage kt+2
    __builtin_amdgcn_s_barrier();
    if (kt < nkv - 1) {
      int nx = kt + 2;
      if (nx > nkv - 1) nx = nkv - 1;       // clamp: uniform 4-load count
      STAGE(nx * 128, Ks[cur], Vs[cur]);    // overwrite retired buffer
      asm volatile("s_waitcnt vmcnt(4)" ::: "memory");  // tile kt+1 landed
    } else {
      asm volatile("s_waitcnt vmcnt(0)" ::: "memory");  // drain
    }
    __builtin_amdgcn_s_barrier();
  }

  float inv = __builtin_amdgcn_rcpf(lrow);
#pragma unroll
  for (int dt = 0; dt < 4; dt++) {
    bf16x4 o4;
#pragma unroll
    for (int r = 0; r < 4; r++) o4[r] = (__bf16)(po[dt][r] * inv);
    *reinterpret_cast<bf16x4*>(
        O + (size_t)(b * S_ + qg) * D_ + h * HD_ + dt * 16 + g * 4) = o4;
  }
#undef STAGE
}

extern "C" void kernel_launch(void* const* d_in, const int* in_sizes, int n_in,
                              void* d_out, int out_size, void* d_ws, size_t ws_size,
                              hipStream_t stream) {
  const float* x  = (const float*)d_in[0];
  const float* wq = (const float*)d_in[1];
  const float* wk = (const float*)d_in[2];
  const float* wv = (const float*)d_in[3];
  const float* wo = (const float*)d_in[4];
  float* out = (float*)d_out;

  char* w = (char*)d_ws;
  __bf16* xb  = (__bf16*)(w);                    // 8 MB
  __bf16* wqb = (__bf16*)(w + (8u  << 20));      // 2 MB each
  __bf16* wkb = (__bf16*)(w + (10u << 20));
  __bf16* wvb = (__bf16*)(w + (12u << 20));
  __bf16* wob = (__bf16*)(w + (14u << 20));
  __bf16* qws = (__bf16*)(w + (16u << 20));      // 8 MB each
  __bf16* kws = (__bf16*)(w + (24u << 20));
  __bf16* vtw = (__bf16*)(w + (32u << 20));      // V, stored TRANSPOSED [bh][d][s]
  __bf16* aws = (__bf16*)(w + (40u << 20));      // attn out, [token][feature]
  float*  tab = (float*)(w + (48u << 20));       // 512 KB rope table

  cvt_all_kernel<<<4352, 256, 0, stream>>>(x, wq, wk, wv, wo,
                                           xb, wqb, wkb, wvb, wob, tab);
  gemm_qkv<<<dim3(32, 16, 3), 512, 0, stream>>>(xb, wqb, wkb, wvb,
                                                qws, kws, vtw, tab);
  attn_kernel<<<512, 512, 0, stream>>>(qws, kws, vtw, aws);
  gemm_bt0<<<dim3(M_ / 128, D_ / 64), 512, 0, stream>>>(aws, wob, out);
}

// Round 18
// 105.490 us; speedup vs baseline: 1.0809x; 1.0809x over previous
//
#include <hip/hip_runtime.h>
#include <hip/hip_bf16.h>
#include <stdint.h>

typedef __attribute__((ext_vector_type(4))) float f32x4;
typedef __attribute__((ext_vector_type(8))) __bf16 bf16x8;
typedef __attribute__((ext_vector_type(4))) __bf16 bf16x4;

#define DEVI __device__ __forceinline__

static constexpr int S_  = 2048;
static constexpr int D_  = 1024;
static constexpr int H_  = 16;
static constexpr int HD_ = 64;
static constexpr int M_  = 2 * S_;   // B*S = 4096 token rows
static constexpr float SCL2 = 0.18033688f;  // 0.125 * log2(e)

DEVI void gload_lds16(const void* gsrc, void* ldst) {
  __builtin_amdgcn_global_load_lds(
      (__attribute__((address_space(1))) void*)(void*)gsrc,
      (__attribute__((address_space(3))) void*)ldst, 16, 0, 0);
}

DEVI float fexp2(float x) {
  float r;
  asm("v_exp_f32 %0, %1" : "=v"(r) : "v"(x));
  return r;
}

// Fused conversion kernel: x + 4 weights fp32->bf16 (32B-read/16B-write per
// thread: both sides at the coalescing sweet spot), plus RoPE table.
__global__ __launch_bounds__(256) void cvt_all_kernel(
    const float* __restrict__ x, const float* __restrict__ wq,
    const float* __restrict__ wk, const float* __restrict__ wv,
    const float* __restrict__ wo,
    __bf16* __restrict__ xb, __bf16* __restrict__ wqb,
    __bf16* __restrict__ wkb, __bf16* __restrict__ wvb,
    __bf16* __restrict__ wob, float* __restrict__ tab) {
  int blk = blockIdx.x;
  if (blk < 4096) {
    int i = blk * 256 + threadIdx.x;     // float8 index (1M total)
    const float* src; __bf16* dst; int off;
    if (i < (1 << 19))                      { src = x;  dst = xb;  off = 0; }
    else if (i < (1 << 19) + (1 << 17))     { src = wq; dst = wqb; off = (1 << 19); }
    else if (i < (1 << 19) + 2 * (1 << 17)) { src = wk; dst = wkb; off = (1 << 19) + (1 << 17); }
    else if (i < (1 << 19) + 3 * (1 << 17)) { src = wv; dst = wvb; off = (1 << 19) + 2 * (1 << 17); }
    else                                    { src = wo; dst = wob; off = (1 << 19) + 3 * (1 << 17); }
    int j = i - off;
    float4 v0 = reinterpret_cast<const float4*>(src)[2 * j];
    float4 v1 = reinterpret_cast<const float4*>(src)[2 * j + 1];
    bf16x8 o;
    o[0] = (__bf16)v0.x; o[1] = (__bf16)v0.y; o[2] = (__bf16)v0.z; o[3] = (__bf16)v0.w;
    o[4] = (__bf16)v1.x; o[5] = (__bf16)v1.y; o[6] = (__bf16)v1.z; o[7] = (__bf16)v1.w;
    reinterpret_cast<bf16x8*>(dst)[j] = o;
  } else {
    int i = (blk - 4096) * 256 + threadIdx.x;   // 0..65535 = S*32
    int s = i >> 5, f = i & 31;
    float freq = powf(10000.0f, -(float)(2 * f) / (float)HD_);
    float ang = (float)s * freq;
    tab[2 * i]     = cosf(ang);
    tab[2 * i + 1] = sinf(ang);
  }
}

// ---------------------------------------------------------------------------
// QKV GEMM: m97 128x128 BK=32 structure, 512-thread / 8-wave blocks
// (wave grid 2M x 4N). Best measured (round 11/16): 40.6 us, 635 TF.
// Per-barrier MFMA density (8 MFMA/wave/iter) beats higher-occupancy
// retiles (r17: 128x64 regressed to 50.6 despite 58% occupancy).
// z=0/1 -> RoPE + head-split (Q pre-scaled by SCL2);
// z=2 -> V written DIRECTLY TRANSPOSED as Vt[bh][d][s].
// ---------------------------------------------------------------------------
__global__ __launch_bounds__(512, 6) void gemm_qkv(
    const __bf16* __restrict__ A, const __bf16* __restrict__ W0,
    const __bf16* __restrict__ W1, const __bf16* __restrict__ W2,
    __bf16* __restrict__ Cq, __bf16* __restrict__ Ck, __bf16* __restrict__ Cvt,
    const float* __restrict__ tab) {
  __shared__ __attribute__((aligned(16))) __bf16 As[128 * 32];
  __shared__ __attribute__((aligned(16))) __bf16 Bs[128 * 32];
  const int tid  = threadIdx.x;
  const int lane = tid & 63;
  const int wv   = tid >> 6;           // 0..7
  const int wr   = wv >> 2;            // 0..1 (M strip of 64)
  const int wc   = wv & 3;             // 0..3 (N strip of 32)
  const int m0 = blockIdx.x * 128;
  const int n0 = blockIdx.y * 128;
  const int z  = blockIdx.z;
  const __bf16* W = (z == 0) ? W0 : (z == 1 ? W1 : W2);
  const int arow = lane & 15;
  const int kgrp = (lane >> 4) * 8;

  f32x4 acc[4][2];
#pragma unroll
  for (int i = 0; i < 4; i++)
#pragma unroll
    for (int j = 0; j < 2; j++) acc[i][j] = f32x4{0.f, 0.f, 0.f, 0.f};

  for (int k0 = 0; k0 < 1024; k0 += 32) {
    __syncthreads();
    {
      int c   = wv * 64 + lane;        // chunk 0..511 (whole tile)
      int row = c >> 2;
      int kc  = (c & 3) * 8;
      gload_lds16(A + (size_t)(m0 + row) * 1024 + k0 + kc, As + wv * 512);
      gload_lds16(W + (size_t)(n0 + row) * 1024 + k0 + kc, Bs + wv * 512);
    }
    asm volatile("s_waitcnt vmcnt(0)" ::: "memory");
    __syncthreads();
    bf16x8 af[4], bw[2];
#pragma unroll
    for (int i = 0; i < 4; i++)
      af[i] = *reinterpret_cast<const bf16x8*>(As + (wr * 64 + i * 16 + arow) * 32 + kgrp);
#pragma unroll
    for (int j = 0; j < 2; j++)
      bw[j] = *reinterpret_cast<const bf16x8*>(Bs + (wc * 32 + j * 16 + arow) * 32 + kgrp);
#pragma unroll
    for (int i = 0; i < 4; i++)
#pragma unroll
      for (int j = 0; j < 2; j++)
        acc[i][j] = __builtin_amdgcn_mfma_f32_16x16x32_bf16(af[i], bw[j], acc[i][j], 0, 0, 0);
  }

  // epilogue. C/D layout: col = lane&15 (n), row = (lane>>4)*4 + r (m)
  if (z == 2) {
#pragma unroll
    for (int i = 0; i < 4; i++) {
      int m = m0 + wr * 64 + i * 16 + (lane >> 4) * 4;
      int bb = m >> 11, srow = m & (S_ - 1);
#pragma unroll
      for (int j = 0; j < 2; j++) {
        int n = n0 + wc * 32 + j * 16 + arow;
        int h = n >> 6, d = n & 63;
        bf16x4 o4;
#pragma unroll
        for (int r = 0; r < 4; r++) o4[r] = (__bf16)acc[i][j][r];
        *reinterpret_cast<bf16x4*>(
            Cvt + ((size_t)(bb * H_ + h) * HD_ + d) * S_ + srow) = o4;
      }
    }
  } else {
#pragma unroll
    for (int i = 0; i < 4; i++) {
#pragma unroll
      for (int j = 0; j < 2; j++) {
#pragma unroll
        for (int r = 0; r < 4; r++) {
          int m = m0 + wr * 64 + i * 16 + (lane >> 4) * 4 + r;
          int n = n0 + wc * 32 + j * 16 + arow;
          float v = acc[i][j][r];
          int bb = m >> 11, srow = m & (S_ - 1);
          int h = n >> 6, d = n & 63;
          size_t oidx = ((size_t)(bb * H_ + h) * S_ + srow) * HD_ + d;
          float other = __shfl_xor(v, 1, 64);   // n bit0 == lane bit0
          int fq = d >> 1;
          float2 cssn = *reinterpret_cast<const float2*>(tab + (srow * 32 + fq) * 2);
          float rv = (d & 1) ? (other * cssn.y + v * cssn.x)
                             : (v * cssn.x - other * cssn.y);
          if (z == 0) rv *= SCL2;   // pre-scale Q: logits in exp2 domain
          ((z == 0) ? Cq : Ck)[oidx] = (__bf16)rv;
        }
      }
    }
  }
}

// ---------------------------------------------------------------------------
// O-projection: tile 128x64, 512-thread / 8-wave blocks. Proven round-11
// kernel, unchanged.
// ---------------------------------------------------------------------------
__global__ __launch_bounds__(512, 4) void gemm_bt0(
    const __bf16* __restrict__ A, const __bf16* __restrict__ W0,
    float* __restrict__ Cf) {
  __shared__ __attribute__((aligned(16))) __bf16 As[128 * 32];
  __shared__ __attribute__((aligned(16))) __bf16 Bs[64 * 32];
  const int tid  = threadIdx.x;
  const int lane = tid & 63;
  const int wv   = tid >> 6;
  const int wr   = wv >> 1;            // 0..3 (M strip of 32)
  const int wc   = wv & 1;             // 0..1 (N strip of 32)
  const int m0 = blockIdx.x * 128;
  const int n0 = blockIdx.y * 64;
  const int arow = lane & 15;
  const int kgrp = (lane >> 4) * 8;

  f32x4 acc[2][2];
#pragma unroll
  for (int i = 0; i < 2; i++)
#pragma unroll
    for (int j = 0; j < 2; j++) acc[i][j] = f32x4{0.f, 0.f, 0.f, 0.f};

  for (int k0 = 0; k0 < 1024; k0 += 32) {
    __syncthreads();
    {
      int c   = wv * 64 + lane;        // 0..511 -> A rows 0..127
      int row = c >> 2;
      int kc  = (c & 3) * 8;
      gload_lds16(A + (size_t)(m0 + row) * 1024 + k0 + kc, As + wv * 512);
      if (wv < 4)                      // 0..255 -> B rows 0..63
        gload_lds16(W0 + (size_t)(n0 + row) * 1024 + k0 + kc, Bs + wv * 512);
    }
    asm volatile("s_waitcnt vmcnt(0)" ::: "memory");
    __syncthreads();
    bf16x8 af[2], bw[2];
#pragma unroll
    for (int i = 0; i < 2; i++)
      af[i] = *reinterpret_cast<const bf16x8*>(As + (wr * 32 + i * 16 + arow) * 32 + kgrp);
#pragma unroll
    for (int j = 0; j < 2; j++)
      bw[j] = *reinterpret_cast<const bf16x8*>(Bs + (wc * 32 + j * 16 + arow) * 32 + kgrp);
#pragma unroll
    for (int i = 0; i < 2; i++)
#pragma unroll
      for (int j = 0; j < 2; j++)
        acc[i][j] = __builtin_amdgcn_mfma_f32_16x16x32_bf16(af[i], bw[j], acc[i][j], 0, 0, 0);
  }

#pragma unroll
  for (int i = 0; i < 2; i++)
#pragma unroll
    for (int j = 0; j < 2; j++)
#pragma unroll
      for (int r = 0; r < 4; r++) {
        int m = m0 + wr * 32 + i * 16 + (lane >> 4) * 4 + r;
        int n = n0 + wc * 32 + j * 16 + arow;
        Cf[(size_t)m * D_ + n] = acc[i][j][r];
      }
}

// ---------------------------------------------------------------------------
// Flash attention, causal. Round-14 version (best measured): 512 linear
// blocks, 8 waves each, one 128-row Q-tile per block; heavy/light halves
// for LPT-style balance; tree softmax; KVBLK=128; counted vmcnt(4) dbuf.
// ---------------------------------------------------------------------------
__global__ __launch_bounds__(512, 4) void attn_kernel(
    const __bf16* __restrict__ Q, const __bf16* __restrict__ K,
    const __bf16* __restrict__ Vt, __bf16* __restrict__ O) {
  __shared__ __attribute__((aligned(16))) __bf16 Ks[2][128 * 64];
  __shared__ __attribute__((aligned(16))) __bf16 Vs[2][64 * 128];
  const int tid = threadIdx.x, lane = tid & 63, wv = tid >> 6;  // wv 0..7
  const int id   = blockIdx.x;        // 0..511
  const int half = id >> 8;           // 0 = heavy tiles, 1 = light tiles
  const int sub  = id & 255;
  const int bh   = sub & 31;
  const int pr   = sub >> 5;          // 0..7
  const int qt   = half ? pr : 15 - pr;   // heavy half dispatched first
  const int b = bh >> 4, h = bh & 15;
  const __bf16* Qb  = Q  + (size_t)bh * S_ * HD_;
  const __bf16* Kb  = K  + (size_t)bh * S_ * HD_;
  const __bf16* Vtb = Vt + (size_t)bh * HD_ * S_;
  const int arow = lane & 15, g = lane >> 4;

  // 4 gload_lds16 per thread per 128-key tile (2 K-chunks + 2 V-chunks)
#define STAGE(K0, BK_, BV_)                                                   \
  do {                                                                        \
    _Pragma("unroll") for (int j = 0; j < 2; ++j) {                           \
      int c = (wv * 2 + j) * 64 + lane;          /* chunk 0..1023 */          \
      int rowk = c >> 3, qqk = c & 7;                                         \
      int qsk = qqk ^ (rowk & 7);                                             \
      int ctp = rowk >> 4, rw = rowk & 15;                                    \
      int kph = ((ctp & 4) << 4) + ((ctp & 2) << 4) + ((ctp & 1) << 2)        \
                + ((rw >> 2) << 3) + (rw & 3);                                \
      gload_lds16(Kb + (size_t)((K0) + kph) * HD_ + qsk * 8,                  \
                  (BK_) + (size_t)(wv * 2 + j) * 512);                        \
      int rowv = c >> 4, qqv = c & 15;                                        \
      int qsv = qqv ^ (rowv & 7);                                             \
      gload_lds16(Vtb + (size_t)rowv * S_ + (K0) + qsv * 8,                   \
                  (BV_) + (size_t)(wv * 2 + j) * 512);                        \
    }                                                                         \
  } while (0)

  const int q0 = qt * 128;
  const int nkv = qt + 1;                     // 128-key tiles
  const int qw = q0 + wv * 16;
  const int qg = qw + arow;                   // this thread's q-row

  bf16x8 aq[2];
#pragma unroll
  for (int j = 0; j < 2; j++)
    aq[j] = *reinterpret_cast<const bf16x8*>(
        Qb + (size_t)(qw + arow) * HD_ + j * 32 + g * 8);

  f32x4 po[4];
#pragma unroll
  for (int dt = 0; dt < 4; dt++) po[dt] = f32x4{0.f, 0.f, 0.f, 0.f};
  float mrow = -1e30f, lrow = 0.f;

  // prologue: stage tiles 0 and 1 (clamped); vmcnt(4) -> tile 0 landed
  STAGE(0, Ks[0], Vs[0]);
  {
    int t1 = (nkv > 1) ? 128 : 0;
    STAGE(t1, Ks[1], Vs[1]);
  }
  asm volatile("s_waitcnt vmcnt(4)" ::: "memory");
  __builtin_amdgcn_s_barrier();

  for (int kt = 0; kt < nkv; ++kt) {
    const int k0 = kt * 128;
    const int cur = kt & 1;
    const __bf16* Kc = Ks[cur];
    const __bf16* Vc = Vs[cur];

    // S^T = K Q^T : D[key][q], 16 MFMA over 128 keys
    f32x4 sc4[8];
    __builtin_amdgcn_s_setprio(1);
#pragma unroll
    for (int ct = 0; ct < 8; ct++) {
      sc4[ct] = f32x4{0.f, 0.f, 0.f, 0.f};
      int L = ct * 16 + arow;
#pragma unroll
      for (int j2 = 0; j2 < 2; j2++) {
        int byt = (L * 128 + j2 * 64 + g * 16) ^ ((L & 7) << 4);
        bf16x8 kb = *reinterpret_cast<const bf16x8*>((const char*)Kc + byt);
        sc4[ct] = __builtin_amdgcn_mfma_f32_16x16x32_bf16(kb, aq[j2], sc4[ct], 0, 0, 0);
      }
    }
    __builtin_amdgcn_s_setprio(0);

    // causal mask (last tile only). physical key of sc4[ct][r]:
    // k0 + (ct&4)*16 + (ct&2)*16 + (ct&1)*4 + g*8 + r
    if (kt == nkv - 1) {
#pragma unroll
      for (int ct = 0; ct < 8; ct++) {
        int kb0 = k0 + ((ct & 4) << 4) + ((ct & 2) << 4) + ((ct & 1) << 2) + g * 8;
#pragma unroll
        for (int r = 0; r < 4; r++)
          if (kb0 + r > qg) sc4[ct][r] = -1e30f;
      }
    }

    // in-register online softmax (one q-row per lane, 32 values), tree max
    float mc[8];
#pragma unroll
    for (int ct = 0; ct < 8; ct++)
      mc[ct] = fmaxf(fmaxf(sc4[ct][0], sc4[ct][1]),
                     fmaxf(sc4[ct][2], sc4[ct][3]));
#pragma unroll
    for (int sstep = 4; sstep > 0; sstep >>= 1)
#pragma unroll
      for (int ct = 0; ct < sstep; ct++) mc[ct] = fmaxf(mc[ct], mc[ct + sstep]);
    float mx = mc[0];
    mx = fmaxf(mx, __shfl_xor(mx, 16, 64));
    mx = fmaxf(mx, __shfl_xor(mx, 32, 64));

    bool noskip = !__all(mx <= mrow + 11.0f);
    if (noskip) {
      float mnew = fmaxf(mrow, mx);
      float corr = fexp2(mrow - mnew);
      mrow = mnew;
      lrow *= corr;
#pragma unroll
      for (int dt = 0; dt < 4; dt++)
#pragma unroll
        for (int r = 0; r < 4; r++) po[dt][r] *= corr;
    }

    // exp + tree sum
    float rc[8];
#pragma unroll
    for (int ct = 0; ct < 8; ct++) {
      float e0 = fexp2(sc4[ct][0] - mrow);
      float e1 = fexp2(sc4[ct][1] - mrow);
      float e2 = fexp2(sc4[ct][2] - mrow);
      float e3 = fexp2(sc4[ct][3] - mrow);
      sc4[ct][0] = e0; sc4[ct][1] = e1; sc4[ct][2] = e2; sc4[ct][3] = e3;
      rc[ct] = (e0 + e1) + (e2 + e3);
    }
#pragma unroll
    for (int sstep = 4; sstep > 0; sstep >>= 1)
#pragma unroll
      for (int ct = 0; ct < sstep; ct++) rc[ct] += rc[ct + sstep];
    float rs = rc[0];
    rs += __shfl_xor(rs, 16, 64);
    rs += __shfl_xor(rs, 32, 64);
    lrow += rs;

    // pack P: pb[jj] holds physical keys jj*32 + g*8 .. +7 (lane-local)
    bf16x8 pb[4];
#pragma unroll
    for (int h2 = 0; h2 < 2; h2++)
#pragma unroll
      for (int j2 = 0; j2 < 2; j2++) {
#pragma unroll
        for (int r = 0; r < 4; r++) {
          pb[h2 * 2 + j2][r]     = (__bf16)sc4[h2 * 4 + 2 * j2][r];
          pb[h2 * 2 + j2][4 + r] = (__bf16)sc4[h2 * 4 + 2 * j2 + 1][r];
        }
      }

    // O^T += V^T P^T : po[dt] = D[d][q], d = dt*16 + g*4 + r, q = arow
    __builtin_amdgcn_s_setprio(1);
#pragma unroll
    for (int dt = 0; dt < 4; dt++) {
      int d = dt * 16 + arow;
#pragma unroll
      for (int jj = 0; jj < 4; jj++) {
        int byv = (d * 256 + jj * 64 + g * 16) ^ ((d & 7) << 4);
        bf16x8 vb = *reinterpret_cast<const bf16x8*>((const char*)Vc + byv);
        po[dt] = __builtin_amdgcn_mfma_f32_16x16x32_bf16(vb, pb[jj], po[dt], 0, 0, 0);
      }
    }
    __builtin_amdgcn_s_setprio(0);

    // pipeline tail: all waves done reading buf[cur], then stage kt+2
    __builtin_amdgcn_s_barrier();
    if (kt < nkv - 1) {
      int nx = kt + 2;
      if (nx > nkv - 1) nx = nkv - 1;       // clamp: uniform 4-load count
      STAGE(nx * 128, Ks[cur], Vs[cur]);    // overwrite retired buffer
      asm volatile("s_waitcnt vmcnt(4)" ::: "memory");  // tile kt+1 landed
    } else {
      asm volatile("s_waitcnt vmcnt(0)" ::: "memory");  // drain
    }
    __builtin_amdgcn_s_barrier();
  }

  float inv = __builtin_amdgcn_rcpf(lrow);
#pragma unroll
  for (int dt = 0; dt < 4; dt++) {
    bf16x4 o4;
#pragma unroll
    for (int r = 0; r < 4; r++) o4[r] = (__bf16)(po[dt][r] * inv);
    *reinterpret_cast<bf16x4*>(
        O + (size_t)(b * S_ + qg) * D_ + h * HD_ + dt * 16 + g * 4) = o4;
  }
#undef STAGE
}

extern "C" void kernel_launch(void* const* d_in, const int* in_sizes, int n_in,
                              void* d_out, int out_size, void* d_ws, size_t ws_size,
                              hipStream_t stream) {
  const float* x  = (const float*)d_in[0];
  const float* wq = (const float*)d_in[1];
  const float* wk = (const float*)d_in[2];
  const float* wv = (const float*)d_in[3];
  const float* wo = (const float*)d_in[4];
  float* out = (float*)d_out;

  char* w = (char*)d_ws;
  __bf16* xb  = (__bf16*)(w);                    // 8 MB
  __bf16* wqb = (__bf16*)(w + (8u  << 20));      // 2 MB each
  __bf16* wkb = (__bf16*)(w + (10u << 20));
  __bf16* wvb = (__bf16*)(w + (12u << 20));
  __bf16* wob = (__bf16*)(w + (14u << 20));
  __bf16* qws = (__bf16*)(w + (16u << 20));      // 8 MB each
  __bf16* kws = (__bf16*)(w + (24u << 20));
  __bf16* vtw = (__bf16*)(w + (32u << 20));      // V, stored TRANSPOSED [bh][d][s]
  __bf16* aws = (__bf16*)(w + (40u << 20));      // attn out, [token][feature]
  float*  tab = (float*)(w + (48u << 20));       // 512 KB rope table

  cvt_all_kernel<<<4352, 256, 0, stream>>>(x, wq, wk, wv, wo,
                                           xb, wqb, wkb, wvb, wob, tab);
  gemm_qkv<<<dim3(32, 8, 3), 512, 0, stream>>>(xb, wqb, wkb, wvb,
                                               qws, kws, vtw, tab);
  attn_kernel<<<512, 512, 0, stream>>>(qws, kws, vtw, aws);
  gemm_bt0<<<dim3(M_ / 128, D_ / 64), 512, 0, stream>>>(aws, wob, out);
}